// Round 1
// baseline (1139.079 us; speedup 1.0000x reference)
//
#include <hip/hip_runtime.h>

// Problem constants (fixed by the reference): n=2048 rows, f=32 features.
// Output row = [emb_in[i] (32) | emb_in[j] (32) | sum_weights[j] (1)] = 65 floats.
// i = row >> 11, j = row & 2047.  Output: 2048*2048*65 = 272,629,760 floats (~1.09 GB).
#define N_ROWS 2048
#define N_SHIFT 11      // log2(N_ROWS)
#define FEAT 32
#define ROW_LEN 65      // 2*FEAT + 1

__global__ __launch_bounds__(256) void expand_kernel(
    const float* __restrict__ emb,   // [2048*32]
    const float* __restrict__ w,     // [2048]
    float4* __restrict__ out,        // out_size/4 float4s
    unsigned int num4)
{
    unsigned int t = blockIdx.x * blockDim.x + threadIdx.x;
    if (t >= num4) return;

    unsigned int e0 = t * 4u;
    float r[4];
#pragma unroll
    for (int k = 0; k < 4; ++k) {
        unsigned int e   = e0 + (unsigned int)k;
        unsigned int row = e / 65u;            // compiler emits magic mul_hi + shift
        unsigned int col = e - row * 65u;
        unsigned int j   = row & (N_ROWS - 1u);
        unsigned int i   = row >> N_SHIFT;

        // Branchless source select: one predicated load per element.
        bool isw = (col >= 64u);
        unsigned int idx_emb = (col < 32u) ? ((i << 5) + col)
                                           : ((j << 5) + (col - 32u));
        const float* p   = isw ? w : emb;
        unsigned int idx = isw ? j : idx_emb;
        r[k] = p[idx];                         // L1/L2 hit: input is 264 KB total
    }

    float4 v;
    v.x = r[0]; v.y = r[1]; v.z = r[2]; v.w = r[3];
    out[t] = v;                                // 16 B coalesced store
}

extern "C" void kernel_launch(void* const* d_in, const int* in_sizes, int n_in,
                              void* d_out, int out_size, void* d_ws, size_t ws_size,
                              hipStream_t stream) {
    const float* emb = (const float*)d_in[0];   // [2048, 32] f32
    const float* w   = (const float*)d_in[1];   // [2048] f32
    float4* out      = (float4*)d_out;          // [2048*2048, 65] f32

    unsigned int num4 = (unsigned int)(out_size / 4);   // 68,157,440 (exact)
    unsigned int blocks = (num4 + 255u) / 256u;
    expand_kernel<<<dim3(blocks), dim3(256), 0, stream>>>(emb, w, out, num4);
}

// Round 2
// 1092.520 us; speedup vs baseline: 1.0426x; 1.0426x over previous
//
#include <hip/hip_runtime.h>

// n=2048 rows, f=32 features. Output row r = [emb[i] (32) | emb[j] (32) | w[j]],
// i = r>>11, j = r&2047. Output 2048*2048*65 floats = 1.09 GB — write-BW bound.
//
// Strategy: block = 256 threads builds a 64-row tile (64*65 = 4160 floats,
// 16,640 B) as a contiguous image in LDS, then drains LDS->global with
// unit-stride float4 (ds_read_b128 + global_store_dwordx4). Tiles are 64-row
// aligned => i constant per tile, j = j0..j0+63 contiguous (no wrap, no div).
// Fill-phase global loads are unit-stride 128 B segments (emb[i] hoisted,
// loaded once per wave). All gathering happens conflict-free in LDS.

#define NROWS 2048
#define TILE_ROWS 64
#define TILE_FLOATS (TILE_ROWS * 65)   // 4160
#define TILE_F4 (TILE_FLOATS / 4)      // 1040 float4s, exact

__global__ __launch_bounds__(256) void expand_lds(
    const float* __restrict__ emb,   // [2048*32]
    const float* __restrict__ sw,    // [2048]
    float4* __restrict__ out)        // flat output as float4
{
    __shared__ __align__(16) float lds[TILE_FLOATS];

    const unsigned tile = blockIdx.x;
    const unsigned tid  = threadIdx.x;
    const unsigned wave = tid >> 6;     // 0..3
    const unsigned lane = tid & 63u;

    const unsigned r0 = tile * TILE_ROWS;
    const unsigned i  = r0 >> 11;            // constant per tile (64 | 2048)
    const unsigned j0 = r0 & (NROWS - 1u);   // j0..j0+63, never wraps

    // emb[i] is shared by all 64 rows of the tile: load once per wave.
    const float vi = (lane < 32u) ? emb[i * 32u + lane] : 0.0f;

    // Fill: each wave handles 16 rows (row rr = 4*it + wave).
#pragma unroll
    for (unsigned it = 0; it < TILE_ROWS / 4; ++it) {
        const unsigned rr = it * 4u + wave;
        const unsigned j  = j0 + rr;
        // lanes 0..31: emb[i][lane] (register); lanes 32..63: emb[j][lane-32]
        // (coalesced 128 B segment, L2-hot).
        float v = (lane < 32u) ? vi : emb[j * 32u + (lane - 32u)];
        lds[rr * 65u + lane] = v;            // consecutive lanes -> no conflicts
        if (lane == 0u) lds[rr * 65u + 64u] = sw[j];
    }
    __syncthreads();

    // Drain: 1040 float4s per tile, canonical b128 reads + dwordx4 stores.
    const float4* lds4 = (const float4*)lds;
    const unsigned long long base = (unsigned long long)tile * TILE_F4;
#pragma unroll
    for (unsigned p = 0; p < 5; ++p) {
        const unsigned idx = p * 256u + tid;
        if (idx < TILE_F4)
            out[base + idx] = lds4[idx];
    }
}

extern "C" void kernel_launch(void* const* d_in, const int* in_sizes, int n_in,
                              void* d_out, int out_size, void* d_ws, size_t ws_size,
                              hipStream_t stream) {
    const float* emb = (const float*)d_in[0];   // [2048, 32] f32
    const float* sw  = (const float*)d_in[1];   // [2048] f32
    float4* out      = (float4*)d_out;

    const unsigned tiles = (NROWS * NROWS) / TILE_ROWS;   // 65,536 blocks
    expand_lds<<<dim3(tiles), dim3(256), 0, stream>>>(emb, sw, out);
}